// Round 1
// baseline (127.890 us; speedup 1.0000x reference)
//
#include <hip/hip_runtime.h>
#include <math.h>

#define B 32
#define G 32
#define P 8400
#define NC 80
#define NCAND 27

__device__ __forceinline__ float iou_prior(float gx1, float gy1, float gx2, float gy2, float4 pr) {
    // Matches reference overlaps: union = max(area_g + area_p - inter, 1e-6)
    float ltx = fmaxf(gx1, pr.x), lty = fmaxf(gy1, pr.y);
    float rbx = fminf(gx2, pr.z), rby = fminf(gy2, pr.w);
    float w = fmaxf(rbx - ltx, 0.f), h = fmaxf(rby - lty, 0.f);
    float inter = w * h;
    float ag = (gx2 - gx1) * (gy2 - gy1);
    float ap = (pr.z - pr.x) * (pr.w - pr.y);
    float uni = fmaxf(ag + ap - inter, 1e-6f);
    return inter / uni;
}

// ---- K0: zero the per-(b,p) assignment records -----------------------------
__global__ __launch_bounds__(256) void k_zero(float4* rec, int n) {
    int i = blockIdx.x * 256 + threadIdx.x;
    if (i < n) rec[i] = make_float4(0.f, 0.f, 0.f, 0.f);
}

// ---- K1: per-(b,g) candidate selection (top-9 per level) + ATSS threshold --
__global__ __launch_bounds__(256) void k_cand(const float4* __restrict__ priors,
                                              const float4* __restrict__ gtb,
                                              const float* __restrict__ flagv,
                                              int* __restrict__ cand_idx,
                                              float* __restrict__ cand_pos) {
    __shared__ float dist[P];        // 33.6 KB
    __shared__ float rval[256];
    __shared__ int   ridx[256];
    __shared__ int   cidx[NCAND];
    __shared__ float cov[NCAND];
    __shared__ int   cing[NCAND];
    __shared__ float s_thr;

    const int bg = blockIdx.x;
    const int t = threadIdx.x;

    float flag = flagv[bg];
    if (flag <= 0.f) {
        // padded gt: is_in_candidate all-zero -> no positives possible
        if (t < NCAND) { cand_idx[bg * NCAND + t] = 0; cand_pos[bg * NCAND + t] = 0.f; }
        return;
    }

    float4 gt = gtb[bg];
    float gcx = (gt.x + gt.z) * 0.5f, gcy = (gt.y + gt.w) * 0.5f;

    for (int p = t; p < P; p += 256) {
        float4 pr = priors[p];
        float dx = gcx - (pr.x + pr.z) * 0.5f;
        float dy = gcy - (pr.y + pr.w) * 0.5f;
        dist[p] = sqrtf(dx * dx + dy * dy);
    }
    __syncthreads();

    const int starts[3] = {0, 6400, 8000};
    const int counts[3] = {6400, 1600, 400};

    for (int l = 0; l < 3; ++l) {
        int s = starts[l], n = counts[l];
        for (int r = 0; r < 9; ++r) {
            // argmin over [s, s+n), tie -> smallest index (lax.top_k stable order)
            float bv = 3.4e38f; int bi = 0x7fffffff;
            for (int p = s + t; p < s + n; p += 256) {
                float v = dist[p];
                if (v < bv) { bv = v; bi = p; }
            }
            rval[t] = bv; ridx[t] = bi;
            __syncthreads();
            if (t < 64) {
                float v = rval[t]; int i = ridx[t];
#pragma unroll
                for (int k = 1; k < 4; ++k) {
                    float v2 = rval[t + 64 * k]; int i2 = ridx[t + 64 * k];
                    if (v2 < v || (v2 == v && i2 < i)) { v = v2; i = i2; }
                }
#pragma unroll
                for (int off = 32; off > 0; off >>= 1) {
                    float v2 = __shfl_down(v, off, 64);
                    int   i2 = __shfl_down(i, off, 64);
                    if (v2 < v || (v2 == v && i2 < i)) { v = v2; i = i2; }
                }
                if (t == 0) { cidx[l * 9 + r] = i; dist[i] = 3.4e38f; }
            }
            __syncthreads();
        }
    }

    // overlaps + center-in-gt only at the 27 candidates
    if (t < NCAND) {
        int p = cidx[t];
        float4 pr = priors[p];
        cov[t] = iou_prior(gt.x, gt.y, gt.z, gt.w, pr);
        float pcx = (pr.x + pr.z) * 0.5f, pcy = (pr.y + pr.w) * 0.5f;
        float m = fminf(fminf(pcx - gt.x, pcy - gt.y), fminf(gt.z - pcx, gt.w - pcy));
        cing[t] = (m > 1e-9f) ? 1 : 0;
    }
    __syncthreads();
    if (t == 0) {
        float mean = 0.f;
        for (int j = 0; j < NCAND; ++j) mean += cov[j];
        mean /= (float)NCAND;
        float var = 0.f;
        for (int j = 0; j < NCAND; ++j) { float d = cov[j] - mean; var += d * d; }
        var /= (float)(NCAND - 1);          // ddof=1
        s_thr = mean + sqrtf(var);
    }
    __syncthreads();
    if (t < NCAND) {
        float pos = (cov[t] > s_thr && cing[t]) ? 1.f : 0.f;
        cand_idx[bg * NCAND + t] = cidx[t];
        cand_pos[bg * NCAND + t] = pos;
    }
}

// ---- K2: per-image resolution of multi-assigned priors ---------------------
__global__ __launch_bounds__(256) void k_resolve(const float4* __restrict__ priors,
                                                 const float4* __restrict__ gtb,
                                                 const float4* __restrict__ predb,
                                                 const int* __restrict__ gtl,
                                                 const int* __restrict__ cand_idx,
                                                 const float* __restrict__ cand_pos,
                                                 float4* __restrict__ rec) {
    __shared__ int cnt[P];           // 33.6 KB
    const int b = blockIdx.x;
    const int t = threadIdx.x;

    for (int i = t; i < P; i += 256) cnt[i] = 0;
    __syncthreads();

    const int base = b * G * NCAND;
    for (int e = t; e < G * NCAND; e += 256) {
        if (cand_pos[base + e] > 0.f) atomicAdd(&cnt[cand_idx[base + e]], 1);
    }
    __syncthreads();

    for (int e = t; e < G * NCAND; e += 256) {
        if (cand_pos[base + e] <= 0.f) continue;
        int p = cand_idx[base + e];
        int g = e / NCAND;
        int gi = g;
        if (cnt[p] > 1) {
            // multi-assigned: argmax over ALL g of IoU(gt, prior[p]), tie -> first
            float4 pr = priors[p];
            float best = -1.f; gi = 0;
            for (int g2 = 0; g2 < G; ++g2) {
                float4 gt2 = gtb[b * G + g2];
                float ov = iou_prior(gt2.x, gt2.y, gt2.z, gt2.w, pr);
                if (ov > best) { best = ov; gi = g2; }
            }
            // duplicates at same p compute identical gi -> identical record (benign)
        }
        float4 gt = gtb[b * G + gi];
        float4 pd = predb[b * P + p];
        // reference stage-7 IoU: clipped areas, +1e-9 in denominator
        float ltx = fmaxf(gt.x, pd.x), lty = fmaxf(gt.y, pd.y);
        float rbx = fminf(gt.z, pd.z), rby = fminf(gt.w, pd.w);
        float iw = fmaxf(rbx - ltx, 0.f), ih = fmaxf(rby - lty, 0.f);
        float inter = iw * ih;
        float ag = fmaxf(gt.z - gt.x, 0.f) * fmaxf(gt.w - gt.y, 0.f);
        float ap = fmaxf(pd.z - pd.x, 0.f) * fmaxf(pd.w - pd.y, 0.f);
        float iou = inter / (ag + ap - inter + 1e-9f);
        int lab = gtl[b * G + gi];
        rec[b * P + p] = make_float4(1.f, (float)gi, iou, (float)lab);
    }
}

// ---- K3a: dense scores (one-hot * iou), float4-coalesced -------------------
__global__ __launch_bounds__(256) void k_scores(const float4* __restrict__ rec,
                                                float4* __restrict__ scores) {
    int tid = blockIdx.x * 256 + threadIdx.x;   // over B*P*20, exact grid
    int bp = tid / 20;
    int q = tid % 20;
    float4 r = rec[bp];
    float4 o = make_float4(0.f, 0.f, 0.f, 0.f);
    if (r.x > 0.f) {
        int lab = (int)r.w;
        int c0 = q * 4;
        if (lab >= c0 && lab < c0 + 4) {
            (&o.x)[lab - c0] = r.z;
        }
    }
    scores[tid] = o;
}

// ---- K3b: labels, boxes, fg_mask -------------------------------------------
__global__ __launch_bounds__(256) void k_misc(const float4* __restrict__ rec,
                                              const float4* __restrict__ gtb,
                                              float* __restrict__ labels,
                                              float4* __restrict__ boxes,
                                              float* __restrict__ fgm) {
    int bp = blockIdx.x * 256 + threadIdx.x;    // over B*P, exact grid
    int b = bp / P;
    float4 r = rec[bp];
    bool fg = r.x > 0.f;
    int gi = fg ? (int)r.y : 0;                 // background: argmax(all-zero) = 0
    labels[bp] = fg ? r.w : (float)NC;
    boxes[bp] = gtb[b * G + gi];
    fgm[bp] = fg ? 1.f : 0.f;
}

extern "C" void kernel_launch(void* const* d_in, const int* in_sizes, int n_in,
                              void* d_out, int out_size, void* d_ws, size_t ws_size,
                              hipStream_t stream) {
    const float4* priors = (const float4*)d_in[0];
    // d_in[1] = num_level_priors (compile-time constants here)
    const int*    gtl    = (const int*)d_in[2];
    const float4* gtb    = (const float4*)d_in[3];
    const float*  flagv  = (const float*)d_in[4];
    const float4* predb  = (const float4*)d_in[5];

    char* wsb = (char*)d_ws;
    float4* rec      = (float4*)wsb;                                   // B*P*16 B
    int*    cand_idx = (int*)(wsb + (size_t)B * P * 16);               // B*G*27*4 B
    float*  cand_pos = (float*)(wsb + (size_t)B * P * 16 + (size_t)B * G * NCAND * 4);

    float*  out    = (float*)d_out;
    float*  labels = out;                                  // B*P
    float4* boxes  = (float4*)(out + B * P);               // B*P*4
    float4* scores = (float4*)(out + B * P + B * P * 4);   // B*P*80
    float*  fgm    = out + B * P + B * P * 4 + B * P * NC; // B*P

    hipLaunchKernelGGL(k_zero,    dim3((B * P + 255) / 256), dim3(256), 0, stream, rec, B * P);
    hipLaunchKernelGGL(k_cand,    dim3(B * G),               dim3(256), 0, stream, priors, gtb, flagv, cand_idx, cand_pos);
    hipLaunchKernelGGL(k_resolve, dim3(B),                   dim3(256), 0, stream, priors, gtb, predb, gtl, cand_idx, cand_pos, rec);
    hipLaunchKernelGGL(k_scores,  dim3(B * P * 20 / 256),    dim3(256), 0, stream, rec, scores);
    hipLaunchKernelGGL(k_misc,    dim3(B * P / 256),         dim3(256), 0, stream, rec, gtb, labels, boxes, fgm);
}